// Round 3
// baseline (156.910 us; speedup 1.0000x reference)
//
#include <hip/hip_runtime.h>

#define TT 16384
#define DD 2048
#define EE 64

typedef __attribute__((ext_vector_type(8))) short bf16x8;
typedef __attribute__((ext_vector_type(4))) float f32x4;

__device__ __forceinline__ ushort bf16_rne(float f) {
    unsigned u = __float_as_uint(f);
    return (ushort)((u + 0x7FFFu + ((u >> 16) & 1u)) >> 16);
}
__device__ __forceinline__ float bf16_f32(ushort h) {
    return __uint_as_float(((unsigned)h) << 16);
}

// ---------------------------------------------------------------------------
// Convert W [2048][64] f32 -> W^T hi/lo bf16 [64][2048] (A-operand row-major).
__global__ __launch_bounds__(256)
void wconv(const float* __restrict__ wg, ushort* __restrict__ whiT,
           ushort* __restrict__ wloT) {
    int i = (int)blockIdx.x * 8192 + threadIdx.x;
#pragma unroll 8
    for (int j = 0; j < 32; ++j, i += 256) {
        const float f = wg[i];
        const ushort h = bf16_rne(f);
        const ushort l = bf16_rne(f - bf16_f32(h));
        const int k = i >> 6, e = i & 63;
        whiT[e * DD + k] = h;
        wloT[e * DD + k] = l;
    }
}

// ---------------------------------------------------------------------------
// Fused gate GEMM (bf16x3 MFMA) + biased top-2 + softmax + per-block bins.
// K-split x4: block = 4 waves on the SAME 16 tokens, wave q covers
// k in [512q, 512q+512).  Grid 1024 = 4 blocks/CU -> 16 waves/CU.
// Partials reduced via LDS; wave 0 does top-2 / softmax / bins.
// Frag map (validated round 2): A row = lane&15 (W expert row), B col =
// lane&15 (token), k = (lane>>4)*8 + j; D col = lane&15, row=(lane>>4)*4+reg.
__global__ __launch_bounds__(256, 4)
void gate_fused(const float* __restrict__ x, const ushort* __restrict__ whiT,
                const ushort* __restrict__ wloT, const float* __restrict__ loads,
                float* __restrict__ out, float* __restrict__ binpart) {
    const int tid = threadIdx.x;
    const int lane = tid & 63;
    const int q = tid >> 6;              // k-quarter
    const int col = lane & 15;           // token col / W row within 16-tile
    const int kg = (lane >> 4) * 8;      // k-subgroup
    const int tok = (int)blockIdx.x * 16 + col;

    const float* xr = x + (size_t)tok * DD + q * 512;
    const ushort* ah = whiT + (size_t)col * DD + q * 512;
    const ushort* al = wloT + (size_t)col * DD + q * 512;

    f32x4 acc[4] = {{0,0,0,0},{0,0,0,0},{0,0,0,0},{0,0,0,0}};

    // 4-deep prefetch ring (fully unrolled loop -> static indices).
    float4 pa[4], pb[4];
#pragma unroll
    for (int i = 0; i < 4; ++i) {
        pa[i] = *(const float4*)(xr + i * 32 + kg);
        pb[i] = *(const float4*)(xr + i * 32 + kg + 4);
    }

#pragma unroll
    for (int kk = 0; kk < 16; ++kk) {
        const float4 ca = pa[kk & 3], cb = pb[kk & 3];
        if (kk + 4 < 16) {
            pa[kk & 3] = *(const float4*)(xr + (kk + 4) * 32 + kg);
            pb[kk & 3] = *(const float4*)(xr + (kk + 4) * 32 + kg + 4);
        }
        const float cf[8] = {ca.x, ca.y, ca.z, ca.w, cb.x, cb.y, cb.z, cb.w};
        bf16x8 bhi, blo;
#pragma unroll
        for (int j = 0; j < 8; ++j) {
            const ushort h = bf16_rne(cf[j]);
            bhi[j] = (short)h;
            blo[j] = (short)bf16_rne(cf[j] - bf16_f32(h));
        }
#pragma unroll
        for (int m = 0; m < 4; ++m) {
            const bf16x8 fh = *(const bf16x8*)(ah + (size_t)(m * 16) * DD + kk * 32 + kg);
            const bf16x8 fl = *(const bf16x8*)(al + (size_t)(m * 16) * DD + kk * 32 + kg);
            acc[m] = __builtin_amdgcn_mfma_f32_16x16x32_bf16(fh, bhi, acc[m], 0, 0, 0);
            acc[m] = __builtin_amdgcn_mfma_f32_16x16x32_bf16(fh, blo, acc[m], 0, 0, 0);
            acc[m] = __builtin_amdgcn_mfma_f32_16x16x32_bf16(fl, bhi, acc[m], 0, 0, 0);
        }
    }

    // ---- K-split reduction through LDS --------------------------------
    __shared__ float accbuf[4][64][16];  // 16 KB
    __shared__ float bins[64];
#pragma unroll
    for (int m = 0; m < 4; ++m)
        *(f32x4*)&accbuf[q][lane][m * 4] = acc[m];
    if (tid < 64) bins[tid] = 0.0f;
    __syncthreads();
    if (q != 0) return;

    f32x4 r[4];
#pragma unroll
    for (int m = 0; m < 4; ++m) {
        f32x4 s = *(const f32x4*)&accbuf[0][lane][m * 4];
#pragma unroll
        for (int w = 1; w < 4; ++w) {
            const f32x4 t = *(const f32x4*)&accbuf[w][lane][m * 4];
            s.x += t.x; s.y += t.y; s.z += t.z; s.w += t.w;
        }
        r[m] = s;
    }

    // ---- top-2 (biased), lane holds e = m*16 + (lane>>4)*4 + rr -------
    const int erow = (lane >> 4) * 4;
    float v1 = -3.4e38f, u1 = 0.0f, v2 = -3.4e38f, u2 = 0.0f;
    int i1 = 0x7fffffff, i2 = 0x7fffffff;
#pragma unroll
    for (int m = 0; m < 4; ++m)
#pragma unroll
        for (int rr = 0; rr < 4; ++rr) {
            const int e = m * 16 + erow + rr;
            const float u = r[m][rr];
            const float b = u - (loads[e] - 0.015625f) * 2.0f;
            if ((b > v1) || (b == v1 && e < i1)) {
                v2 = v1; u2 = u1; i2 = i1;
                v1 = b;  u1 = u;  i1 = e;
            } else if ((b > v2) || (b == v2 && e < i2)) {
                v2 = b; u2 = u; i2 = e;
            }
        }
#pragma unroll
    for (int s = 0; s < 2; ++s) {
        const int mask = 16 << s;
        const float ov1 = __shfl_xor(v1, mask), ou1 = __shfl_xor(u1, mask);
        const float ov2 = __shfl_xor(v2, mask), ou2 = __shfl_xor(u2, mask);
        const int oi1 = __shfl_xor(i1, mask), oi2 = __shfl_xor(i2, mask);
        if ((ov1 > v1) || (ov1 == v1 && oi1 < i1)) {
            if ((v1 > ov2) || (v1 == ov2 && i1 < oi2)) { v2 = v1; u2 = u1; i2 = i1; }
            else                                        { v2 = ov2; u2 = ou2; i2 = oi2; }
            v1 = ov1; u1 = ou1; i1 = oi1;
        } else if ((ov1 > v2) || (ov1 == v2 && oi1 < i2)) {
            v2 = ov1; u2 = ou1; i2 = oi1;
        }
    }

    if (lane < 16) {
        const float mx = fmaxf(u1, u2);
        const float e1 = __expf(u1 - mx), e2 = __expf(u2 - mx);
        const float w1 = e1 / (e1 + e2), w2 = e2 / (e1 + e2);
        *(float2*)(out + 2 * tok) = make_float2(w1, w2);
        *(float2*)(out + 2 * TT + 2 * tok) = make_float2((float)i1, (float)i2);
        atomicAdd(&bins[i1], w1);
        atomicAdd(&bins[i2], w2);
    }
    binpart[(size_t)blockIdx.x * 64 + lane] = bins[lane];
}

// ---------------------------------------------------------------------------
// Sum 1024 per-block bins + EMA load update (deterministic order).
__global__ __launch_bounds__(256)
void finalize(const float* __restrict__ binpart, const float* __restrict__ loads,
              float* __restrict__ out) {
    __shared__ float p[256];
    const int e = threadIdx.x & 63, q = threadIdx.x >> 6;
    float s = 0.0f;
    for (int b = q * 256; b < (q + 1) * 256; ++b) s += binpart[(size_t)b * 64 + e];
    p[threadIdx.x] = s;
    __syncthreads();
    if (q == 0) {
        const float tot = p[e] + p[64 + e] + p[128 + e] + p[192 + e];
        out[4 * TT + e] = 0.9f * loads[e] + 0.1f * (tot * (1.0f / 16384.0f));
    }
}

// ---------------------------------------------------------------------------
extern "C" void kernel_launch(void* const* d_in, const int* in_sizes, int n_in,
                              void* d_out, int out_size, void* d_ws, size_t ws_size,
                              hipStream_t stream) {
    const float* x = (const float*)d_in[0];      // [16384, 2048]
    const float* wg = (const float*)d_in[1];     // [2048, 64]
    const float* loads = (const float*)d_in[2];  // [64]
    float* out = (float*)d_out;

    ushort* whiT = (ushort*)d_ws;                       // [64][2048] bf16 hi
    ushort* wloT = whiT + (size_t)EE * DD;              // [64][2048] bf16 lo
    float* binpart = (float*)(wloT + (size_t)EE * DD);  // [1024][64]

    hipLaunchKernelGGL(wconv, dim3(16), dim3(256), 0, stream, wg, whiT, wloT);
    hipLaunchKernelGGL(gate_fused, dim3(1024), dim3(256), 0, stream,
                       x, whiT, wloT, loads, out, binpart);
    hipLaunchKernelGGL(finalize, dim3(1), dim3(256), 0, stream,
                       binpart, loads, out);
}

// Round 4
// 48.908 us; speedup vs baseline: 3.2083x; 3.2083x over previous
//
#include <hip/hip_runtime.h>

#define TT 16384
#define DD 2048
#define EE 64

typedef __attribute__((ext_vector_type(8))) short bf16x8;
typedef __attribute__((ext_vector_type(8))) unsigned short ushort8;
typedef __attribute__((ext_vector_type(4))) float f32x4;

__device__ __forceinline__ unsigned short bf16_rne(float f) {
    unsigned u = __float_as_uint(f);
    return (unsigned short)((u + 0x7FFFu + ((u >> 16) & 1u)) >> 16);
}
__device__ __forceinline__ float bf16_f32(unsigned short h) {
    return __uint_as_float(((unsigned)h) << 16);
}

__device__ __forceinline__ void gload16(void* lds, const void* g) {
    __builtin_amdgcn_global_load_lds(
        (const __attribute__((address_space(1))) unsigned int*)g,
        (__attribute__((address_space(3))) unsigned int*)lds, 16, 0, 0);
}

// ---------------------------------------------------------------------------
// W [2048][64] f32 -> wpack: A-fragments in load order.
// wpack[K0][h][m][lane][j] = bf16(hi/lo) of wg[(K0*32+(lane>>4)*8+j)*64 + m*16+(lane&15)]
// One wave's (h,m) frag for k-step K0 is a contiguous, coalesced 1 KB row.
__global__ __launch_bounds__(256)
void wconv(const float* __restrict__ wg, unsigned short* __restrict__ wpack) {
    const int t = (int)blockIdx.x * 256 + threadIdx.x;  // 32768 threads
    const int K0 = t >> 9, h = (t >> 8) & 1, m = (t >> 6) & 3, lane = t & 63;
    const int e = m * 16 + (lane & 15);
    const int ks = K0 * 32 + (lane >> 4) * 8;
    ushort8 v;
#pragma unroll
    for (int j = 0; j < 8; ++j) {
        const float f = wg[(size_t)(ks + j) * EE + e];
        const unsigned short hi = bf16_rne(f);
        v[j] = h ? bf16_rne(f - bf16_f32(hi)) : hi;
    }
    *(ushort8*)(wpack + ((size_t)(K0 * 8 + h * 4 + m) * 64 + lane) * 8) = v;
}

// ---------------------------------------------------------------------------
// Fused gate GEMM + biased top-2 + softmax + per-wave bins.
// 512 thr = 8 waves: tg=w>>1 owns tokens [tg*16,tg*16+16), q=w&1 owns K-half.
// x: global_load_lds -> 3-ring LDS (16 KB/step), source-side XOR chunk swizzle.
// W: register ring from wpack (coalesced 16B/lane, L2-hot).
// Counted vmcnt (never 0 in loop) + raw s_barrier = T3/T4-lite pipeline.
__global__ __launch_bounds__(512, 2)
void gate_fused(const float* __restrict__ x, const unsigned short* __restrict__ wpack,
                const float* __restrict__ loads, float* __restrict__ out,
                float* __restrict__ binpart) {
    __shared__ __align__(16) float arena[3 * 4096];  // 3 ring bufs x (2q x 2048 f32)
    __shared__ float bins[4][64];

    const int tid = threadIdx.x, lane = tid & 63, w = tid >> 6;
    const int tg = w >> 1, q = w & 1;
    const int tb = (int)blockIdx.x;

    f32x4 acc[4] = {{0,0,0,0},{0,0,0,0},{0,0,0,0},{0,0,0,0}};

    // ---- stage x step s into ring buffer rb: 16 instrs/block, 2/wave ------
    auto stage_x = [&](int s, float* rb) {
#pragma unroll
        for (int i = 0; i < 2; ++i) {
            const int n = (w << 1) | i;          // 0..15
            const int qh = n >> 3, g = n & 7;    // K-half, token row-group
            const int r = (g << 3) + (lane >> 3);
            const int c = (lane & 7) ^ ((lane >> 3) & 7);  // src chunk swizzle
            gload16(rb + qh * 2048 + g * 256,
                    x + (size_t)(tb * 64 + r) * DD + qh * 1024 + s * 32 + c * 4);
        }
    };
    // ---- W-frag register loads for step t (this wave's K-half) -----------
    auto loadW = [&](int t, bf16x8 (&wh)[4], bf16x8 (&wl)[4]) {
        const unsigned short* base = wpack + (size_t)((q << 5) + t) * 4096 + lane * 8;
#pragma unroll
        for (int m = 0; m < 4; ++m) {
            wh[m] = *(const bf16x8*)(base + (size_t)m * 512);
            wl[m] = *(const bf16x8*)(base + (size_t)(4 + m) * 512);
        }
    };
    // ---- one K-step of MFMA from LDS x + register W ----------------------
    auto compute = [&](const float* xq, bf16x8 (&wh)[4], bf16x8 (&wl)[4]) {
        const int col = lane & 15;
        const int row = (tg << 4) + col;
        const int kgc = (lane >> 4) << 1;
        const int sw = row & 7;
        const f32x4 va = *(const f32x4*)(xq + ((row << 3) + (kgc ^ sw)) * 4);
        const f32x4 vb = *(const f32x4*)(xq + ((row << 3) + ((kgc + 1) ^ sw)) * 4);
        const float cf[8] = {va.x, va.y, va.z, va.w, vb.x, vb.y, vb.z, vb.w};
        bf16x8 bhi, blo;
#pragma unroll
        for (int j = 0; j < 8; ++j) {
            const unsigned short h = bf16_rne(cf[j]);
            bhi[j] = (short)h;
            blo[j] = (short)bf16_rne(cf[j] - bf16_f32(h));
        }
#pragma unroll
        for (int m = 0; m < 4; ++m) {
            acc[m] = __builtin_amdgcn_mfma_f32_16x16x32_bf16(wh[m], bhi, acc[m], 0, 0, 0);
            acc[m] = __builtin_amdgcn_mfma_f32_16x16x32_bf16(wh[m], blo, acc[m], 0, 0, 0);
            acc[m] = __builtin_amdgcn_mfma_f32_16x16x32_bf16(wl[m], bhi, acc[m], 0, 0, 0);
        }
    };

    float *p0 = arena, *p1 = arena + 4096, *p2 = arena + 8192;
    bf16x8 whA[4], wlA[4], whB[4], wlB[4];

    stage_x(0, p0);
    stage_x(1, p1);
    loadW(0, whA, wlA);
    asm volatile("s_waitcnt vmcnt(10)" ::: "memory");
    __builtin_amdgcn_s_barrier();

    for (int s = 0; s < 30; s += 2) {
        stage_x(s + 2, p2);
        loadW(s + 1, whB, wlB);
        compute(p0 + (q << 11), whA, wlA);
        asm volatile("s_waitcnt vmcnt(10)" ::: "memory");
        __builtin_amdgcn_s_barrier();
        { float* t_ = p0; p0 = p1; p1 = p2; p2 = t_; }

        stage_x(s + 3, p2);
        loadW(s + 2, whA, wlA);
        compute(p0 + (q << 11), whB, wlB);
        asm volatile("s_waitcnt vmcnt(10)" ::: "memory");
        __builtin_amdgcn_s_barrier();
        { float* t_ = p0; p0 = p1; p1 = p2; p2 = t_; }
    }
    loadW(31, whB, wlB);
    compute(p0 + (q << 11), whA, wlA);           // step 30
    asm volatile("s_waitcnt vmcnt(8)" ::: "memory");
    __builtin_amdgcn_s_barrier();
    compute(p1 + (q << 11), whB, wlB);           // step 31

    // ---- K-split reduce through arena overlay (ring buf 0, now free) -----
    float* accb = arena;  // [4 tg][64 lane][16]
    if (q == 1) {
#pragma unroll
        for (int m = 0; m < 4; ++m)
            *(f32x4*)(accb + ((size_t)(tg * 64 + lane) * 16 + m * 4)) = acc[m];
    }
    __syncthreads();
    if (q != 0) return;

    f32x4 r[4];
#pragma unroll
    for (int m = 0; m < 4; ++m) {
        const f32x4 t_ = *(const f32x4*)(accb + ((size_t)(tg * 64 + lane) * 16 + m * 4));
        r[m].x = acc[m].x + t_.x; r[m].y = acc[m].y + t_.y;
        r[m].z = acc[m].z + t_.z; r[m].w = acc[m].w + t_.w;
    }

    // ---- top-2 (biased): lane holds e = m*16 + (lane>>4)*4 + rr ----------
    const int col = lane & 15;
    const int tok = tb * 64 + tg * 16 + col;
    const int erow = (lane >> 4) * 4;
    float v1 = -3.4e38f, u1 = 0.0f, v2 = -3.4e38f, u2 = 0.0f;
    int i1 = 0x7fffffff, i2 = 0x7fffffff;
#pragma unroll
    for (int m = 0; m < 4; ++m)
#pragma unroll
        for (int rr = 0; rr < 4; ++rr) {
            const int e = m * 16 + erow + rr;
            const float u = r[m][rr];
            const float b = u - (loads[e] - 0.015625f) * 2.0f;
            if ((b > v1) || (b == v1 && e < i1)) {
                v2 = v1; u2 = u1; i2 = i1;
                v1 = b;  u1 = u;  i1 = e;
            } else if ((b > v2) || (b == v2 && e < i2)) {
                v2 = b; u2 = u; i2 = e;
            }
        }
#pragma unroll
    for (int s = 0; s < 2; ++s) {
        const int mask = 16 << s;
        const float ov1 = __shfl_xor(v1, mask), ou1 = __shfl_xor(u1, mask);
        const float ov2 = __shfl_xor(v2, mask), ou2 = __shfl_xor(u2, mask);
        const int oi1 = __shfl_xor(i1, mask), oi2 = __shfl_xor(i2, mask);
        if ((ov1 > v1) || (ov1 == v1 && oi1 < i1)) {
            if ((v1 > ov2) || (v1 == ov2 && i1 < oi2)) { v2 = v1; u2 = u1; i2 = i1; }
            else                                        { v2 = ov2; u2 = ou2; i2 = oi2; }
            v1 = ov1; u1 = ou1; i1 = oi1;
        } else if ((ov1 > v2) || (ov1 == v2 && oi1 < i2)) {
            v2 = ov1; u2 = ou1; i2 = oi1;
        }
    }

    bins[tg][lane] = 0.0f;
    if (lane < 16) {
        const float mx = fmaxf(u1, u2);
        const float e1 = __expf(u1 - mx), e2 = __expf(u2 - mx);
        const float w1 = e1 / (e1 + e2), w2 = e2 / (e1 + e2);
        *(float2*)(out + 2 * tok) = make_float2(w1, w2);
        *(float2*)(out + 2 * TT + 2 * tok) = make_float2((float)i1, (float)i2);
        atomicAdd(&bins[tg][i1], w1);
        atomicAdd(&bins[tg][i2], w2);
    }
    binpart[(size_t)(tb * 4 + tg) * 64 + lane] = bins[tg][lane];
}

// ---------------------------------------------------------------------------
// Deterministic two-stage bin reduction + EMA.
__global__ __launch_bounds__(256)
void finalize1(const float* __restrict__ binpart, float* __restrict__ binmid) {
    __shared__ float p[4][64];
    const int e = threadIdx.x & 63, sub = threadIdx.x >> 6;
    float s = 0.0f;
#pragma unroll 4
    for (int r = 0; r < 16; ++r)
        s += binpart[(size_t)(((int)blockIdx.x * 4 + sub) * 16 + r) * 64 + e];
    p[sub][e] = s;
    __syncthreads();
    if (sub == 0)
        binmid[(int)blockIdx.x * 64 + e] = ((p[0][e] + p[1][e]) + p[2][e]) + p[3][e];
}

__global__ __launch_bounds__(64)
void finalize2(const float* __restrict__ binmid, const float* __restrict__ loads,
               float* __restrict__ out) {
    const int e = threadIdx.x;
    float s = 0.0f;
#pragma unroll
    for (int j = 0; j < 16; ++j) s += binmid[j * 64 + e];
    out[4 * TT + e] = 0.9f * loads[e] + 0.1f * (s * (1.0f / 16384.0f));
}

// ---------------------------------------------------------------------------
extern "C" void kernel_launch(void* const* d_in, const int* in_sizes, int n_in,
                              void* d_out, int out_size, void* d_ws, size_t ws_size,
                              hipStream_t stream) {
    const float* x = (const float*)d_in[0];      // [16384, 2048]
    const float* wg = (const float*)d_in[1];     // [2048, 64]
    const float* loads = (const float*)d_in[2];  // [64]
    float* out = (float*)d_out;

    unsigned short* wpack = (unsigned short*)d_ws;            // 512 KB
    float* binpart = (float*)(wpack + (size_t)64 * 8 * 64 * 8);  // [1024][64]
    float* binmid = binpart + 1024 * 64;                      // [16][64]

    hipLaunchKernelGGL(wconv, dim3(128), dim3(256), 0, stream, wg, wpack);
    hipLaunchKernelGGL(gate_fused, dim3(256), dim3(512), 0, stream,
                       x, wpack, loads, out, binpart);
    hipLaunchKernelGGL(finalize1, dim3(16), dim3(256), 0, stream, binpart, binmid);
    hipLaunchKernelGGL(finalize2, dim3(1), dim3(64), 0, stream, binmid, loads, out);
}

// Round 5
// 45.484 us; speedup vs baseline: 3.4498x; 1.0753x over previous
//
#include <hip/hip_runtime.h>

#define TT 16384
#define DD 2048
#define EE 64

typedef __attribute__((ext_vector_type(8))) short bf16x8;
typedef __attribute__((ext_vector_type(8))) unsigned short ushort8;
typedef __attribute__((ext_vector_type(4))) float f32x4;

__device__ __forceinline__ unsigned short bf16_rne(float f) {
    unsigned u = __float_as_uint(f);
    return (unsigned short)((u + 0x7FFFu + ((u >> 16) & 1u)) >> 16);
}
__device__ __forceinline__ float bf16_f32(unsigned short h) {
    return __uint_as_float(((unsigned)h) << 16);
}
__device__ __forceinline__ unsigned cvt_pk(float lo, float hi) {
    unsigned r;
    asm("v_cvt_pk_bf16_f32 %0, %1, %2" : "=v"(r) : "v"(lo), "v"(hi));
    return r;  // low16 = bf16(lo), high16 = bf16(hi)
}
__device__ __forceinline__ bf16x8 pack4(unsigned a, unsigned b, unsigned c, unsigned d) {
    union { unsigned u[4]; bf16x8 v; } t;
    t.u[0] = a; t.u[1] = b; t.u[2] = c; t.u[3] = d;
    return t.v;
}
__device__ __forceinline__ void gload16(void* lds, const void* g) {
    __builtin_amdgcn_global_load_lds(
        (const __attribute__((address_space(1))) unsigned int*)g,
        (__attribute__((address_space(3))) unsigned int*)lds, 16, 0, 0);
}

// ---------------------------------------------------------------------------
// W [2048][64] f32 -> wpack: A-fragments in exact load order.
// wpack[K0][h][m][lane][j] = bf16 hi/lo of wg[(K0*32+(lane>>4)*8+j)*64 + m*16+(lane&15)]
__global__ __launch_bounds__(256)
void wconv(const float* __restrict__ wg, unsigned short* __restrict__ wpack) {
    const int t = (int)blockIdx.x * 256 + threadIdx.x;  // 32768 threads
    const int K0 = t >> 9, h = (t >> 8) & 1, m = (t >> 6) & 3, lane = t & 63;
    const int e = m * 16 + (lane & 15);
    const int ks = K0 * 32 + (lane >> 4) * 8;
    ushort8 v;
#pragma unroll
    for (int j = 0; j < 8; ++j) {
        const float f = wg[(size_t)(ks + j) * EE + e];
        const unsigned short hi = bf16_rne(f);
        v[j] = h ? bf16_rne(f - bf16_f32(hi)) : hi;
    }
    *(ushort8*)(wpack + ((size_t)(K0 * 8 + h * 4 + m) * 64 + lane) * 8) = v;
}

// ---------------------------------------------------------------------------
// Fused gate GEMM + biased top-2 + softmax + per-tg bins.
// 512 thr = 8 waves = 2 token-groups (16 tokens each) x 4-way K-split.
// Grid 512 = 2 blocks/CU = 16 waves/CU: two independent barrier domains per
// CU hide each other's stage/barrier stalls.  x: global_load_lds 3-ring
// (16 KB/step, source-side XOR swizzle, linear LDS).  W: 2-slot register
// ring from wpack (L2-hot, coalesced 16 B/lane).  Counted vmcnt(10).
__global__ __launch_bounds__(512, 4)
void gate_fused(const float* __restrict__ x, const unsigned short* __restrict__ wpack,
                const float* __restrict__ loads, float* __restrict__ out,
                float* __restrict__ binpart) {
    __shared__ __align__(16) float arena[3 * 4096];  // 48 KB: 3-ring, 16 KB/step
    __shared__ float bins[2][64];

    const int tid = threadIdx.x, lane = tid & 63, w = tid >> 6;
    const int tg = w >> 2, q = w & 3;   // token-group, K-quarter
    const int tb = (int)blockIdx.x;

    f32x4 acc[4] = {{0,0,0,0},{0,0,0,0},{0,0,0,0},{0,0,0,0}};

    // stage step s (k = qw*512 + s*32, all 32 tokens, 4 windows) into rb
    auto stage_x = [&](int s, float* rb) {
#pragma unroll
        for (int i = 0; i < 2; ++i) {
            const int n = (w << 1) | i;      // 0..15
            const int qw = n >> 2, g = n & 3;
            const int rowp = lane >> 3;      // 0..7
            const int row = g * 8 + rowp;    // 0..31
            const int c = (lane & 7) ^ rowp; // source-side chunk swizzle
            gload16(rb + qw * 1024 + g * 256,
                    x + (size_t)(tb * 32 + row) * DD + qw * 512 + s * 32 + c * 4);
        }
    };
    auto loadW = [&](int t, bf16x8 (&wh)[4], bf16x8 (&wl)[4]) {
        const unsigned short* base = wpack + (size_t)(q * 16 + t) * 4096 + lane * 8;
#pragma unroll
        for (int m = 0; m < 4; ++m) {
            wh[m] = *(const bf16x8*)(base + (size_t)m * 512);
            wl[m] = *(const bf16x8*)(base + (size_t)(4 + m) * 512);
        }
    };
    auto compute = [&](const float* rb, bf16x8 (&wh)[4], bf16x8 (&wl)[4]) {
        const float* xq = rb + q * 1024;
        const int row = tg * 16 + (lane & 15);
        const int kgc = (lane >> 4) << 1;
        const int sw = row & 7;
        const f32x4 va = *(const f32x4*)(xq + row * 32 + ((kgc) ^ sw) * 4);
        const f32x4 vb = *(const f32x4*)(xq + row * 32 + ((kgc + 1) ^ sw) * 4);
        const float cf[8] = {va.x, va.y, va.z, va.w, vb.x, vb.y, vb.z, vb.w};
        unsigned ph[4], pl[4];
#pragma unroll
        for (int j = 0; j < 4; ++j) {
            ph[j] = cvt_pk(cf[2 * j], cf[2 * j + 1]);
            const float h0 = __uint_as_float(ph[j] << 16);
            const float h1 = __uint_as_float(ph[j] & 0xFFFF0000u);
            pl[j] = cvt_pk(cf[2 * j] - h0, cf[2 * j + 1] - h1);
        }
        const bf16x8 bhi = pack4(ph[0], ph[1], ph[2], ph[3]);
        const bf16x8 blo = pack4(pl[0], pl[1], pl[2], pl[3]);
#pragma unroll
        for (int m = 0; m < 4; ++m) {
            acc[m] = __builtin_amdgcn_mfma_f32_16x16x32_bf16(wh[m], bhi, acc[m], 0, 0, 0);
            acc[m] = __builtin_amdgcn_mfma_f32_16x16x32_bf16(wh[m], blo, acc[m], 0, 0, 0);
            acc[m] = __builtin_amdgcn_mfma_f32_16x16x32_bf16(wl[m], bhi, acc[m], 0, 0, 0);
        }
    };

    float *p0 = arena, *p1 = arena + 4096, *p2 = arena + 8192;
    bf16x8 whA[4], wlA[4], whB[4], wlB[4];

    stage_x(0, p0);
    stage_x(1, p1);
    loadW(0, whA, wlA);
    asm volatile("s_waitcnt vmcnt(10)" ::: "memory");
    __builtin_amdgcn_s_barrier();

#pragma unroll 1
    for (int s = 0; s < 14; s += 2) {
        stage_x(s + 2, p2);
        loadW(s + 1, whB, wlB);
        compute(p0, whA, wlA);
        asm volatile("s_waitcnt vmcnt(10)" ::: "memory");
        __builtin_amdgcn_s_barrier();
        { float* t_ = p0; p0 = p1; p1 = p2; p2 = t_; }

        stage_x(s + 3, p2);
        loadW(s + 2, whA, wlA);
        compute(p0, whB, wlB);
        asm volatile("s_waitcnt vmcnt(10)" ::: "memory");
        __builtin_amdgcn_s_barrier();
        { float* t_ = p0; p0 = p1; p1 = p2; p2 = t_; }
    }
    loadW(15, whB, wlB);
    compute(p0, whA, wlA);               // step 14
    asm volatile("s_waitcnt vmcnt(8)" ::: "memory");
    __builtin_amdgcn_s_barrier();
    compute(p1, whB, wlB);               // step 15

    // ---- K-split reduction through arena overlay (stride 20: no conflicts)
    __syncthreads();                     // all ds_reads of step 15 done
    float* accb = arena;                 // [3 q'][2 tg][64 lane][20]
    if (q != 0) {
#pragma unroll
        for (int m = 0; m < 4; ++m)
            *(f32x4*)(accb + ((size_t)((q - 1) * 128 + tg * 64 + lane) * 20 + m * 4)) = acc[m];
    }
    __syncthreads();
    if (q != 0) return;

    f32x4 r[4];
#pragma unroll
    for (int m = 0; m < 4; ++m) {
        f32x4 s_ = acc[m];
#pragma unroll
        for (int qq = 0; qq < 3; ++qq) {
            const f32x4 t_ =
                *(const f32x4*)(accb + ((size_t)(qq * 128 + tg * 64 + lane) * 20 + m * 4));
            s_.x += t_.x; s_.y += t_.y; s_.z += t_.z; s_.w += t_.w;
        }
        r[m] = s_;
    }

    // ---- top-2 (biased): lane holds e = m*16 + (lane>>4)*4 + rr ----------
    const int col = lane & 15;
    const int tok = tb * 32 + tg * 16 + col;
    const int erow = (lane >> 4) * 4;
    float v1 = -3.4e38f, u1 = 0.0f, v2 = -3.4e38f, u2 = 0.0f;
    int i1 = 0x7fffffff, i2 = 0x7fffffff;
#pragma unroll
    for (int m = 0; m < 4; ++m)
#pragma unroll
        for (int rr = 0; rr < 4; ++rr) {
            const int e = m * 16 + erow + rr;
            const float u = r[m][rr];
            const float b = u - (loads[e] - 0.015625f) * 2.0f;
            if ((b > v1) || (b == v1 && e < i1)) {
                v2 = v1; u2 = u1; i2 = i1;
                v1 = b;  u1 = u;  i1 = e;
            } else if ((b > v2) || (b == v2 && e < i2)) {
                v2 = b; u2 = u; i2 = e;
            }
        }
#pragma unroll
    for (int s = 0; s < 2; ++s) {
        const int mask = 16 << s;
        const float ov1 = __shfl_xor(v1, mask), ou1 = __shfl_xor(u1, mask);
        const float ov2 = __shfl_xor(v2, mask), ou2 = __shfl_xor(u2, mask);
        const int oi1 = __shfl_xor(i1, mask), oi2 = __shfl_xor(i2, mask);
        if ((ov1 > v1) || (ov1 == v1 && oi1 < i1)) {
            if ((v1 > ov2) || (v1 == ov2 && i1 < oi2)) { v2 = v1; u2 = u1; i2 = i1; }
            else                                        { v2 = ov2; u2 = ou2; i2 = oi2; }
            v1 = ov1; u1 = ou1; i1 = oi1;
        } else if ((ov1 > v2) || (ov1 == v2 && oi1 < i2)) {
            v2 = ov1; u2 = ou1; i2 = oi1;
        }
    }

    bins[tg][lane] = 0.0f;
    if (lane < 16) {
        const float mx = fmaxf(u1, u2);
        const float e1 = __expf(u1 - mx), e2 = __expf(u2 - mx);
        const float w1 = e1 / (e1 + e2), w2 = e2 / (e1 + e2);
        *(float2*)(out + 2 * tok) = make_float2(w1, w2);
        *(float2*)(out + 2 * TT + 2 * tok) = make_float2((float)i1, (float)i2);
        atomicAdd(&bins[tg][i1], w1);
        atomicAdd(&bins[tg][i2], w2);
    }
    binpart[(size_t)(tb * 2 + tg) * 64 + lane] = bins[tg][lane];
}

// ---------------------------------------------------------------------------
// Deterministic two-stage bin reduction + EMA.
__global__ __launch_bounds__(256)
void finalize1(const float* __restrict__ binpart, float* __restrict__ binmid) {
    __shared__ float p[4][64];
    const int e = threadIdx.x & 63, sub = threadIdx.x >> 6;
    float s = 0.0f;
#pragma unroll 4
    for (int r = 0; r < 16; ++r)
        s += binpart[(size_t)(((int)blockIdx.x * 4 + sub) * 16 + r) * 64 + e];
    p[sub][e] = s;
    __syncthreads();
    if (sub == 0)
        binmid[(int)blockIdx.x * 64 + e] = ((p[0][e] + p[1][e]) + p[2][e]) + p[3][e];
}

__global__ __launch_bounds__(64)
void finalize2(const float* __restrict__ binmid, const float* __restrict__ loads,
               float* __restrict__ out) {
    const int e = threadIdx.x;
    float s = 0.0f;
#pragma unroll
    for (int j = 0; j < 16; ++j) s += binmid[j * 64 + e];
    out[4 * TT + e] = 0.9f * loads[e] + 0.1f * (s * (1.0f / 16384.0f));
}

// ---------------------------------------------------------------------------
extern "C" void kernel_launch(void* const* d_in, const int* in_sizes, int n_in,
                              void* d_out, int out_size, void* d_ws, size_t ws_size,
                              hipStream_t stream) {
    const float* x = (const float*)d_in[0];      // [16384, 2048]
    const float* wg = (const float*)d_in[1];     // [2048, 64]
    const float* loads = (const float*)d_in[2];  // [64]
    float* out = (float*)d_out;

    unsigned short* wpack = (unsigned short*)d_ws;               // 512 KB
    float* binpart = (float*)(wpack + (size_t)64 * 8 * 64 * 8);  // [1024][64]
    float* binmid = binpart + 1024 * 64;                         // [16][64]

    hipLaunchKernelGGL(wconv, dim3(128), dim3(256), 0, stream, wg, wpack);
    hipLaunchKernelGGL(gate_fused, dim3(512), dim3(512), 0, stream,
                       x, wpack, loads, out, binpart);
    hipLaunchKernelGGL(finalize1, dim3(16), dim3(256), 0, stream, binpart, binmid);
    hipLaunchKernelGGL(finalize2, dim3(1), dim3(64), 0, stream, binmid, loads, out);
}